// Round 1
// baseline (322.324 us; speedup 1.0000x reference)
//
#include <hip/hip_runtime.h>

#define SLOPE 0.1f

__device__ __forceinline__ float lrelu(float x) { return x > 0.0f ? x : SLOPE * x; }

// ---------------------------------------------------------------------------
// K1: per-(branch,tap) conv GEMM.  f_part[slot][r][c] = sum_e x2d[r+s*16][e] * w[c][dk][e]
// x2d is x viewed as (2048 = L*B, 512).  slot = branch_base + dk, 16 slots total.
// Grid: 256 blocks (16 row-tiles x 16 slots), 256 threads, tile 128x64, micro 8x4.
// ---------------------------------------------------------------------------
__global__ __launch_bounds__(256) void k1_conv_taps(
    const float* __restrict__ x,
    const float* __restrict__ cw0, const float* __restrict__ cw1,
    const float* __restrict__ cw2, const float* __restrict__ cw3,
    float* __restrict__ f_part)
{
    __shared__ float As[128][33];   // stride 33: (8*rowg+rr+k)%32 distinct -> conflict-free
    __shared__ float Ws[32][65];

    const int t   = threadIdx.x;
    const int slot = blockIdx.x >> 4;
    const int r0   = (blockIdx.x & 15) * 128;

    int branch, base;
    if (slot == 0)      { branch = 0; base = 0; }
    else if (slot < 4)  { branch = 1; base = 1; }
    else if (slot < 9)  { branch = 2; base = 4; }
    else                { branch = 3; base = 9; }
    const int dk  = slot - base;
    const int ksz = 2 * branch + 1;            // 1,3,5,7
    const int s   = dk - branch;               // dk - pad
    const float* cw = (branch == 0) ? cw0 : (branch == 1) ? cw1 : (branch == 2) ? cw2 : cw3;
    const float* wtap = cw + dk * 512;
    const int wstride = ksz * 512;

    const int rowg = t >> 4;   // 16 groups * 8 rows = 128
    const int colg = t & 15;   // 16 groups * 4 cols = 64

    float acc[8][4];
    #pragma unroll
    for (int i = 0; i < 8; ++i)
        #pragma unroll
        for (int j = 0; j < 4; ++j) acc[i][j] = 0.0f;

    for (int e0 = 0; e0 < 512; e0 += 32) {
        // stage A tile: 128 rows x 32 e  (rows shifted by s*16, OOB -> 0)
        #pragma unroll
        for (int n = 0; n < 4; ++n) {
            const int q4  = t + 256 * n;       // 1024 float4
            const int row = q4 >> 3;
            const int e4  = (q4 & 7) * 4;
            const int g   = r0 + row + s * 16;
            float4 val = make_float4(0.f, 0.f, 0.f, 0.f);
            if (g >= 0 && g < 2048)
                val = *(const float4*)(x + g * 512 + e0 + e4);
            As[row][e4 + 0] = val.x; As[row][e4 + 1] = val.y;
            As[row][e4 + 2] = val.z; As[row][e4 + 3] = val.w;
        }
        // stage W tile (transposed): 32 k x 64 c
        #pragma unroll
        for (int n = 0; n < 2; ++n) {
            const int q4 = t + 256 * n;        // 512 float4
            const int c  = q4 >> 3;
            const int k4 = (q4 & 7) * 4;
            const float4 wv = *(const float4*)(wtap + c * wstride + e0 + k4);
            Ws[k4 + 0][c] = wv.x; Ws[k4 + 1][c] = wv.y;
            Ws[k4 + 2][c] = wv.z; Ws[k4 + 3][c] = wv.w;
        }
        __syncthreads();
        #pragma unroll 4
        for (int k = 0; k < 32; ++k) {
            float a[8], w[4];
            #pragma unroll
            for (int rr = 0; rr < 8; ++rr) a[rr] = As[rowg * 8 + rr][k];
            #pragma unroll
            for (int cc = 0; cc < 4; ++cc) w[cc] = Ws[k][colg * 4 + cc];
            #pragma unroll
            for (int rr = 0; rr < 8; ++rr)
                #pragma unroll
                for (int cc = 0; cc < 4; ++cc) acc[rr][cc] += a[rr] * w[cc];
        }
        __syncthreads();
    }

    float* fp = f_part + slot * 131072;
    #pragma unroll
    for (int rr = 0; rr < 8; ++rr) {
        const int r = r0 + rowg * 8 + rr;
        float4 vv = make_float4(acc[rr][0], acc[rr][1], acc[rr][2], acc[rr][3]);
        *(float4*)(fp + r * 64 + colg * 4) = vv;
    }
}

// ---------------------------------------------------------------------------
// K2: [u|v] = F_act @ [W1a.T | W1b.T], F_act computed on the fly from f_part
// (tap-sum + conv bias + lrelu fused into A-tile staging).  u gets +mb0.
// Grid: 64 blocks (row-tiles of 32), 256 threads, tile 32x128, micro 4x4.
// ---------------------------------------------------------------------------
__global__ __launch_bounds__(256) void k2_uv(
    const float* __restrict__ f_part,
    const float* __restrict__ cb0, const float* __restrict__ cb1,
    const float* __restrict__ cb2, const float* __restrict__ cb3,
    const float* __restrict__ mw0, const float* __restrict__ mb0,
    float* __restrict__ u, float* __restrict__ v)
{
    __shared__ float As[32][33];
    __shared__ float Ws[32][129];

    const int t  = threadIdx.x;
    const int r0 = blockIdx.x * 32;
    const int rowg = t >> 5;   // 8 * 4 rows = 32
    const int colg = t & 31;   // 32 * 4 cols = 128

    float acc[4][4];
    #pragma unroll
    for (int i = 0; i < 4; ++i)
        #pragma unroll
        for (int j = 0; j < 4; ++j) acc[i][j] = 0.0f;

    for (int m0 = 0; m0 < 256; m0 += 32) {
        // stage A: 32 rows x 32 m, one float4 per thread, fused f activation
        {
            const int row = t >> 3;
            const int m4  = (t & 7) * 4;
            const int m   = m0 + m4;          // whole 32-chunk is inside one branch
            const int branch = m >> 6;
            const int c   = m & 63;
            int base, ksz; const float* cb;
            if (branch == 0)      { base = 0; ksz = 1; cb = cb0; }
            else if (branch == 1) { base = 1; ksz = 3; cb = cb1; }
            else if (branch == 2) { base = 4; ksz = 5; cb = cb2; }
            else                  { base = 9; ksz = 7; cb = cb3; }
            float4 sum = *(const float4*)(cb + c);
            const float* fp = f_part + base * 131072 + (r0 + row) * 64 + c;
            for (int d = 0; d < ksz; ++d) {
                const float4 p = *(const float4*)(fp + d * 131072);
                sum.x += p.x; sum.y += p.y; sum.z += p.z; sum.w += p.w;
            }
            As[row][m4 + 0] = lrelu(sum.x); As[row][m4 + 1] = lrelu(sum.y);
            As[row][m4 + 2] = lrelu(sum.z); As[row][m4 + 3] = lrelu(sum.w);
        }
        // stage W (transposed): 32 k x 128 col; col<64 -> mw0[:, :256], col>=64 -> mw0[:, 256:]
        #pragma unroll
        for (int n = 0; n < 4; ++n) {
            const int q4  = t + 256 * n;      // 1024 float4
            const int col = q4 >> 3;
            const int k4  = (q4 & 7) * 4;
            const int half = col >> 6;
            const int c    = col & 63;
            const float4 wv = *(const float4*)(mw0 + c * 512 + half * 256 + m0 + k4);
            Ws[k4 + 0][col] = wv.x; Ws[k4 + 1][col] = wv.y;
            Ws[k4 + 2][col] = wv.z; Ws[k4 + 3][col] = wv.w;
        }
        __syncthreads();
        #pragma unroll 4
        for (int k = 0; k < 32; ++k) {
            float a[4], w[4];
            #pragma unroll
            for (int rr = 0; rr < 4; ++rr) a[rr] = As[rowg * 4 + rr][k];
            #pragma unroll
            for (int cc = 0; cc < 4; ++cc) w[cc] = Ws[k][colg * 4 + cc];
            #pragma unroll
            for (int rr = 0; rr < 4; ++rr)
                #pragma unroll
                for (int cc = 0; cc < 4; ++cc) acc[rr][cc] += a[rr] * w[cc];
        }
        __syncthreads();
    }

    const int col = colg * 4;
    if (col < 64) {
        const float4 bb = *(const float4*)(mb0 + col);   // fold layer-1 bias into u
        #pragma unroll
        for (int rr = 0; rr < 4; ++rr) {
            const int r = r0 + rowg * 4 + rr;
            float4 o = make_float4(acc[rr][0] + bb.x, acc[rr][1] + bb.y,
                                   acc[rr][2] + bb.z, acc[rr][3] + bb.w);
            *(float4*)(u + r * 64 + col) = o;
        }
    } else {
        #pragma unroll
        for (int rr = 0; rr < 4; ++rr) {
            const int r = r0 + rowg * 4 + rr;
            float4 o = make_float4(acc[rr][0], acc[rr][1], acc[rr][2], acc[rr][3]);
            *(float4*)(v + r * 64 + col - 64) = o;
        }
    }
}

// ---------------------------------------------------------------------------
// K3: per-(j,b): H1[i,:] = lrelu(u[j,b]+v[i,b]); 3x (128x64)@(64x64) lrelu layers;
// S = sum_i H4[i,:]; then head: lrelu(S@lw0.T+lb0) -> lrelu(@lw1.T+lb1) -> out.
// Grid: 2048 blocks (jb = j*16+b), 128 threads, micro 8x8, H kept in LDS fp32.
// ---------------------------------------------------------------------------
__global__ __launch_bounds__(128) void k3_pair(
    const float* __restrict__ u, const float* __restrict__ v,
    const float* __restrict__ mw1, const float* __restrict__ mb1,
    const float* __restrict__ mw2, const float* __restrict__ mb2,
    const float* __restrict__ mw3, const float* __restrict__ mb3,
    const float* __restrict__ lw0, const float* __restrict__ lb0,
    const float* __restrict__ lw1, const float* __restrict__ lb1,
    float* __restrict__ out)
{
    __shared__ float H[128][65];    // stride 65 -> (row+k)%32 banks, conflict-free pattern
    __shared__ float Wl[64][65];
    __shared__ float us[64];
    __shared__ float S2[2][64];
    __shared__ float Ss[64];
    __shared__ float t1s[64];

    const int t  = threadIdx.x;
    const int jb = blockIdx.x;      // j*16 + b
    const int b  = jb & 15;

    if (t < 64) us[t] = u[jb * 64 + t];
    __syncthreads();

    // fill H1 = lrelu(u[j,b] + v[i,b]) : 128 x 64
    #pragma unroll
    for (int n = 0; n < 16; ++n) {
        const int q4 = t + 128 * n;      // 2048 float4
        const int i  = q4 >> 4;
        const int c4 = (q4 & 15) * 4;
        const float4 vv = *(const float4*)(v + (i * 16 + b) * 64 + c4);
        H[i][c4 + 0] = lrelu(vv.x + us[c4 + 0]);
        H[i][c4 + 1] = lrelu(vv.y + us[c4 + 1]);
        H[i][c4 + 2] = lrelu(vv.z + us[c4 + 2]);
        H[i][c4 + 3] = lrelu(vv.w + us[c4 + 3]);
    }

    const int rowg = t >> 3;   // 16 groups * 8 rows = 128
    const int colg = t & 7;    // 8 groups * 8 cols = 64

    const float* Wp[3] = {mw1, mw2, mw3};
    const float* Bp[3] = {mb1, mb2, mb3};

    for (int layer = 0; layer < 3; ++layer) {
        const float* mw = Wp[layer];
        // stage Wl transposed: Wl[k][c] = mw[c*64 + k]
        #pragma unroll
        for (int n = 0; n < 8; ++n) {
            const int q4 = t + 128 * n;   // 1024 float4 = 64 c * 16 k4
            const int c  = q4 >> 4;
            const int k4 = (q4 & 15) * 4;
            const float4 wv = *(const float4*)(mw + c * 64 + k4);
            Wl[k4 + 0][c] = wv.x; Wl[k4 + 1][c] = wv.y;
            Wl[k4 + 2][c] = wv.z; Wl[k4 + 3][c] = wv.w;
        }
        __syncthreads();   // also guards H fill (layer 0) / H rewrite (layer>0)

        float acc[8][8];
        #pragma unroll
        for (int i = 0; i < 8; ++i)
            #pragma unroll
            for (int j = 0; j < 8; ++j) acc[i][j] = 0.0f;

        #pragma unroll 2
        for (int k = 0; k < 64; ++k) {
            float a[8], w[8];
            #pragma unroll
            for (int rr = 0; rr < 8; ++rr) a[rr] = H[rowg * 8 + rr][k];
            #pragma unroll
            for (int cc = 0; cc < 8; ++cc) w[cc] = Wl[k][colg * 8 + cc];
            #pragma unroll
            for (int rr = 0; rr < 8; ++rr)
                #pragma unroll
                for (int cc = 0; cc < 8; ++cc) acc[rr][cc] += a[rr] * w[cc];
        }

        const float* mb = Bp[layer];
        float bb[8];
        #pragma unroll
        for (int cc = 0; cc < 8; ++cc) bb[cc] = mb[colg * 8 + cc];

        __syncthreads();   // all H reads done before overwrite
        #pragma unroll
        for (int rr = 0; rr < 8; ++rr)
            #pragma unroll
            for (int cc = 0; cc < 8; ++cc)
                H[rowg * 8 + rr][colg * 8 + cc] = lrelu(acc[rr][cc] + bb[cc]);
        __syncthreads();
    }

    // S[c] = sum_i H[i][c]
    {
        const int c = t & 63, half = t >> 6;
        float sum = 0.0f;
        #pragma unroll 4
        for (int i = half * 64; i < half * 64 + 64; ++i) sum += H[i][c];
        S2[half][c] = sum;
    }
    __syncthreads();
    if (t < 64) Ss[t] = S2[0][t] + S2[1][t];
    __syncthreads();

    // head layer 1: 64 -> 64
    if (t < 64) {
        float a = lb0[t];
        const float* wr = lw0 + t * 64;
        #pragma unroll 4
        for (int k = 0; k < 64; ++k) a += Ss[k] * wr[k];
        t1s[t] = lrelu(a);
    }
    __syncthreads();

    // head layer 2: 64 -> 256
    #pragma unroll
    for (int n = 0; n < 2; ++n) {
        const int c2 = t + 128 * n;
        float a = lb1[c2];
        const float* wr = lw1 + c2 * 64;
        #pragma unroll 4
        for (int k = 0; k < 64; ++k) a += t1s[k] * wr[k];
        out[jb * 256 + c2] = lrelu(a);
    }
}

// ---------------------------------------------------------------------------
extern "C" void kernel_launch(void* const* d_in, const int* in_sizes, int n_in,
                              void* d_out, int out_size, void* d_ws, size_t ws_size,
                              hipStream_t stream)
{
    const float* x   = (const float*)d_in[0];
    const float* cw0 = (const float*)d_in[1];
    const float* cb0 = (const float*)d_in[2];
    const float* cw1 = (const float*)d_in[3];
    const float* cb1 = (const float*)d_in[4];
    const float* cw2 = (const float*)d_in[5];
    const float* cb2 = (const float*)d_in[6];
    const float* cw3 = (const float*)d_in[7];
    const float* cb3 = (const float*)d_in[8];
    const float* mw0 = (const float*)d_in[9];
    const float* mb0 = (const float*)d_in[10];
    const float* mw1 = (const float*)d_in[11];
    const float* mb1 = (const float*)d_in[12];
    const float* mw2 = (const float*)d_in[13];
    const float* mb2 = (const float*)d_in[14];
    const float* mw3 = (const float*)d_in[15];
    const float* mb3 = (const float*)d_in[16];
    const float* lw0 = (const float*)d_in[17];
    const float* lb0 = (const float*)d_in[18];
    const float* lw1 = (const float*)d_in[19];
    const float* lb1 = (const float*)d_in[20];
    float* out = (float*)d_out;

    // workspace layout (floats): f_part 16*2048*64 (8MB) | u 2048*64 | v 2048*64
    float* f_part = (float*)d_ws;
    float* u = f_part + 16 * 2048 * 64;
    float* v = u + 2048 * 64;

    hipLaunchKernelGGL(k1_conv_taps, dim3(256), dim3(256), 0, stream,
                       x, cw0, cw1, cw2, cw3, f_part);
    hipLaunchKernelGGL(k2_uv, dim3(64), dim3(256), 0, stream,
                       f_part, cb0, cb1, cb2, cb3, mw0, mb0, u, v);
    hipLaunchKernelGGL(k3_pair, dim3(2048), dim3(128), 0, stream,
                       u, v, mw1, mb1, mw2, mb2, mw3, mb3, lw0, lb0, lw1, lb1, out);
}

// Round 2
// 216.711 us; speedup vs baseline: 1.4873x; 1.4873x over previous
//
#include <hip/hip_runtime.h>
#include <hip/hip_bf16.h>

#define SLOPE 0.1f
typedef unsigned short u16;
typedef unsigned int u32;
typedef __attribute__((ext_vector_type(8))) short short8;
typedef __attribute__((ext_vector_type(4))) float floatx4;

__device__ __forceinline__ float lrelu(float x) { return x > 0.0f ? x : SLOPE * x; }

// round-nearest split: x ~= hi + lo (bf16 each), rel err ~2^-17
__device__ __forceinline__ void split_rn(float x, u16* h, u16* l) {
    union { __hip_bfloat16 b; u16 u; } c1, c2;
    c1.b = __float2bfloat16(x);
    float hf = __bfloat162float(c1.b);
    c2.b = __float2bfloat16(x - hf);
    *h = c1.u; *l = c2.u;
}

__device__ __forceinline__ short8 load_frag(const u16* p) {
    union { uint4 q; short8 s; } cv;
    cv.q = *(const uint4*)p;
    return cv.s;
}

// truncation split of 8 fp32 (register) into hi/lo bf16 frags (~2^-16 rel)
__device__ __forceinline__ void split8(const float* xp, short8* hi, short8* lo) {
    union { u32 u[4]; short8 s; } H, L;
    #pragma unroll
    for (int p = 0; p < 4; ++p) {
        u32 b0 = __float_as_uint(xp[2 * p]);
        u32 b1 = __float_as_uint(xp[2 * p + 1]);
        H.u[p] = (b0 >> 16) | (b1 & 0xFFFF0000u);
        float r0 = xp[2 * p]     - __uint_as_float(b0 & 0xFFFF0000u);
        float r1 = xp[2 * p + 1] - __uint_as_float(b1 & 0xFFFF0000u);
        L.u[p] = (__float_as_uint(r0) >> 16) | (__float_as_uint(r1) & 0xFFFF0000u);
    }
    *hi = H.s; *lo = L.s;
}

__device__ __forceinline__ floatx4 mfma16(short8 a, short8 b, floatx4 c) {
    return __builtin_amdgcn_mfma_f32_16x16x32_bf16(a, b, c, 0, 0, 0);
}

// ---------------------------------------------------------------------------
// P0: one-shot preprocessing.
//  seg0: x (2048x512) -> xh/xl bf16
//  seg1: conv weights -> Wc[slot][c=64][e=512] hi/lo (already row-major in e)
//  seg2: mw0 -> B2[n=128][k=256] hi/lo  (n<64: u-half W[:, :256]; n>=64: v-half)
//  seg3: mw1..3 -> W3[layer][n=64][k=64] hi/lo
//  seg4: lw0 -> lw0t[k=64][n=64] fp32 (transposed)
//  seg5: lw1 -> lw1t[k=64][n=256] fp32 (transposed)
// total items = 1048576+524288+32768+12288+4096+16384 = 1638400 = 6400*256
// ---------------------------------------------------------------------------
__global__ __launch_bounds__(256) void p0_prep(
    const float* __restrict__ x,
    const float* __restrict__ cw0, const float* __restrict__ cw1,
    const float* __restrict__ cw2, const float* __restrict__ cw3,
    const float* __restrict__ mw0, const float* __restrict__ mw1,
    const float* __restrict__ mw2, const float* __restrict__ mw3,
    const float* __restrict__ lw0, const float* __restrict__ lw1,
    u16* __restrict__ xh, u16* __restrict__ xl,
    u16* __restrict__ wch, u16* __restrict__ wcl,
    u16* __restrict__ b2h, u16* __restrict__ b2l,
    u16* __restrict__ w3h, u16* __restrict__ w3l,
    float* __restrict__ lw0t, float* __restrict__ lw1t)
{
    int idx = blockIdx.x * 256 + threadIdx.x;
    if (idx < 1048576) { split_rn(x[idx], &xh[idx], &xl[idx]); return; }
    idx -= 1048576;
    if (idx < 524288) {
        const int slot = idx >> 15, c = (idx >> 9) & 63, e = idx & 511;
        int branch, base;
        if (slot == 0)      { branch = 0; base = 0; }
        else if (slot < 4)  { branch = 1; base = 1; }
        else if (slot < 9)  { branch = 2; base = 4; }
        else                { branch = 3; base = 9; }
        const int dk = slot - base, ksz = 2 * branch + 1;
        const float* cw = branch == 0 ? cw0 : branch == 1 ? cw1 : branch == 2 ? cw2 : cw3;
        split_rn(cw[(c * ksz + dk) * 512 + e], &wch[idx], &wcl[idx]);
        return;
    }
    idx -= 524288;
    if (idx < 32768) {
        const int n = idx >> 8, k = idx & 255;
        split_rn(mw0[(n & 63) * 512 + (n >> 6) * 256 + k], &b2h[idx], &b2l[idx]);
        return;
    }
    idx -= 32768;
    if (idx < 12288) {
        const int l = idx >> 12, n = (idx >> 6) & 63, k = idx & 63;
        const float* mw = l == 0 ? mw1 : l == 1 ? mw2 : mw3;
        split_rn(mw[n * 64 + k], &w3h[idx], &w3l[idx]);
        return;
    }
    idx -= 12288;
    if (idx < 4096) { const int k = idx >> 6, n = idx & 63; lw0t[idx] = lw0[n * 64 + k]; return; }
    idx -= 4096;
    if (idx < 16384) { const int k = idx >> 8, n = idx & 255; lw1t[idx] = lw1[n * 64 + k]; return; }
}

// ---------------------------------------------------------------------------
// K1: per-(slot) conv-tap GEMM via MFMA, no LDS.
// f_part[slot][r=2048][c=64] = sum_e x[r + s*16][e] * Wc[slot][c][e]
// grid: 256 blocks (slot*16 + rowtile), 256 thr = 4 waves; wave = 32 rows.
// ---------------------------------------------------------------------------
__global__ __launch_bounds__(256) void k1_conv(
    const u16* __restrict__ xh, const u16* __restrict__ xl,
    const u16* __restrict__ wch, const u16* __restrict__ wcl,
    float* __restrict__ f_part)
{
    const int t = threadIdx.x, lane = t & 63, w = t >> 6;
    const int slot = blockIdx.x >> 4;
    const int m0 = (blockIdx.x & 15) * 128 + w * 32;
    int branch, base;
    if (slot == 0)      { branch = 0; base = 0; }
    else if (slot < 4)  { branch = 1; base = 1; }
    else if (slot < 9)  { branch = 2; base = 4; }
    else                { branch = 3; base = 9; }
    const int s = (slot - base) - branch;       // tap shift in l-units
    const int l15 = lane & 15, quad = lane >> 4;

    const u16* wbh = wch + slot * 32768;
    const u16* wbl = wcl + slot * 32768;

    floatx4 acc[2][4];
    #pragma unroll
    for (int i = 0; i < 2; ++i)
        #pragma unroll
        for (int j = 0; j < 4; ++j) acc[i][j] = (floatx4)0.0f;

    int rowg[2]; bool ok[2];
    #pragma unroll
    for (int mt = 0; mt < 2; ++mt) {
        const int gbase = m0 + mt * 16 + s * 16;   // 16-aligned -> tile uniformly in/out
        ok[mt] = (gbase >= 0) && (gbase < 2048);
        rowg[mt] = gbase + l15;
    }

    const short8 zfrag = {0, 0, 0, 0, 0, 0, 0, 0};
    for (int k0 = 0; k0 < 512; k0 += 32) {
        short8 ah[2], al[2];
        #pragma unroll
        for (int mt = 0; mt < 2; ++mt) {
            if (ok[mt]) {
                const int off = rowg[mt] * 512 + k0 + quad * 8;
                ah[mt] = load_frag(xh + off);
                al[mt] = load_frag(xl + off);
            } else { ah[mt] = zfrag; al[mt] = zfrag; }
        }
        #pragma unroll
        for (int nt = 0; nt < 4; ++nt) {
            const int boff = (nt * 16 + l15) * 512 + k0 + quad * 8;
            const short8 bh = load_frag(wbh + boff);
            const short8 bl = load_frag(wbl + boff);
            #pragma unroll
            for (int mt = 0; mt < 2; ++mt) {
                acc[mt][nt] = mfma16(ah[mt], bh, acc[mt][nt]);
                acc[mt][nt] = mfma16(ah[mt], bl, acc[mt][nt]);
                acc[mt][nt] = mfma16(al[mt], bh, acc[mt][nt]);
            }
        }
    }

    float* fp = f_part + slot * 131072;
    #pragma unroll
    for (int mt = 0; mt < 2; ++mt)
        #pragma unroll
        for (int nt = 0; nt < 4; ++nt)
            #pragma unroll
            for (int r = 0; r < 4; ++r)
                fp[(m0 + mt * 16 + quad * 4 + r) * 64 + nt * 16 + l15] = acc[mt][nt][r];
}

// ---------------------------------------------------------------------------
// K1b: tap-sum + conv bias + lrelu -> F (2048x256) split to bf16 hi/lo.
// 131072 threads, 4 elems each.
// ---------------------------------------------------------------------------
__global__ __launch_bounds__(256) void k1b_act(
    const float* __restrict__ f_part,
    const float* __restrict__ cb0, const float* __restrict__ cb1,
    const float* __restrict__ cb2, const float* __restrict__ cb3,
    u16* __restrict__ Fh, u16* __restrict__ Fl)
{
    const int idx = blockIdx.x * 256 + threadIdx.x;   // 131072
    const int r = idx >> 6, m4 = (idx & 63) * 4;
    const int branch = m4 >> 6, c = m4 & 63;
    int base, ksz; const float* cb;
    if (branch == 0)      { base = 0; ksz = 1; cb = cb0; }
    else if (branch == 1) { base = 1; ksz = 3; cb = cb1; }
    else if (branch == 2) { base = 4; ksz = 5; cb = cb2; }
    else                  { base = 9; ksz = 7; cb = cb3; }
    float4 sum = *(const float4*)(cb + c);
    const float* fp = f_part + base * 131072 + r * 64 + c;
    for (int d = 0; d < ksz; ++d) {
        const float4 p = *(const float4*)(fp + d * 131072);
        sum.x += p.x; sum.y += p.y; sum.z += p.z; sum.w += p.w;
    }
    float v4[4] = {lrelu(sum.x), lrelu(sum.y), lrelu(sum.z), lrelu(sum.w)};
    u16 h4[4], l4[4];
    #pragma unroll
    for (int i = 0; i < 4; ++i) split_rn(v4[i], &h4[i], &l4[i]);
    *(ushort4*)(Fh + r * 256 + m4) = make_ushort4(h4[0], h4[1], h4[2], h4[3]);
    *(ushort4*)(Fl + r * 256 + m4) = make_ushort4(l4[0], l4[1], l4[2], l4[3]);
}

// ---------------------------------------------------------------------------
// K2: [u|v] = F @ B2^T via MFMA, no LDS. M=2048, K=256, N=128 (u cols | v cols).
// grid: (16 rowtiles, 2 n-halves), 256 thr = 4 waves, wave = 32 rows x 64 cols.
// u gets + mb0 (layer-1 bias folded).
// ---------------------------------------------------------------------------
__global__ __launch_bounds__(256) void k2_uv(
    const u16* __restrict__ Fh, const u16* __restrict__ Fl,
    const u16* __restrict__ b2h, const u16* __restrict__ b2l,
    const float* __restrict__ mb0,
    float* __restrict__ u, float* __restrict__ v)
{
    const int t = threadIdx.x, lane = t & 63, w = t >> 6;
    const int m0 = blockIdx.x * 128 + w * 32;
    const int nhalf = blockIdx.y;
    const int l15 = lane & 15, quad = lane >> 4;

    floatx4 acc[2][4];
    #pragma unroll
    for (int i = 0; i < 2; ++i)
        #pragma unroll
        for (int j = 0; j < 4; ++j) acc[i][j] = (floatx4)0.0f;

    for (int k0 = 0; k0 < 256; k0 += 32) {
        short8 ah[2], al[2];
        #pragma unroll
        for (int mt = 0; mt < 2; ++mt) {
            const int off = (m0 + mt * 16 + l15) * 256 + k0 + quad * 8;
            ah[mt] = load_frag(Fh + off);
            al[mt] = load_frag(Fl + off);
        }
        #pragma unroll
        for (int nt = 0; nt < 4; ++nt) {
            const int boff = (nhalf * 64 + nt * 16 + l15) * 256 + k0 + quad * 8;
            const short8 bh = load_frag(b2h + boff);
            const short8 bl = load_frag(b2l + boff);
            #pragma unroll
            for (int mt = 0; mt < 2; ++mt) {
                acc[mt][nt] = mfma16(ah[mt], bh, acc[mt][nt]);
                acc[mt][nt] = mfma16(ah[mt], bl, acc[mt][nt]);
                acc[mt][nt] = mfma16(al[mt], bh, acc[mt][nt]);
            }
        }
    }

    #pragma unroll
    for (int mt = 0; mt < 2; ++mt)
        #pragma unroll
        for (int nt = 0; nt < 4; ++nt) {
            const int c = nt * 16 + l15;
            #pragma unroll
            for (int r = 0; r < 4; ++r) {
                const int row = m0 + mt * 16 + quad * 4 + r;
                const float val = acc[mt][nt][r];
                if (nhalf == 0) u[row * 64 + c] = val + mb0[c];
                else            v[row * 64 + c] = val;
            }
        }
}

// ---------------------------------------------------------------------------
// K3: per (j,b): H1 = lrelu(u[j,b]+v[i,b]) (128x64 in LDS fp32);
// 3 MFMA layers (wave-private 32-row strips, split-bf16 A from LDS, B from
// precomputed global hi/lo); sum over i; fp32 VALU head; write out row.
// grid: 2048 blocks, 256 thr = 4 waves.
// ---------------------------------------------------------------------------
__global__ __launch_bounds__(256) void k3_pair(
    const float* __restrict__ u, const float* __restrict__ v,
    const u16* __restrict__ w3h, const u16* __restrict__ w3l,
    const float* __restrict__ mb1, const float* __restrict__ mb2,
    const float* __restrict__ mb3,
    const float* __restrict__ lw0t, const float* __restrict__ lb0,
    const float* __restrict__ lw1t, const float* __restrict__ lb1,
    float* __restrict__ out)
{
    __shared__ float H[128][68];   // stride 68 words -> 2-way (free) on all patterns
    __shared__ float us[64];
    __shared__ float Sp[4][64];
    __shared__ float Ss[64];
    __shared__ float t1[64];

    const int t = threadIdx.x, lane = t & 63, w = t >> 6;
    const int jb = blockIdx.x, b = jb & 15;
    const int l15 = lane & 15, quad = lane >> 4;
    const int m0 = w * 32;

    if (t < 64) us[t] = u[jb * 64 + t];
    __syncthreads();

    // H1 build: wave-private rows [w*32, w*32+32)
    #pragma unroll
    for (int n = 0; n < 8; ++n) {
        const int idx = lane + 64 * n;            // 512 float4 per wave
        const int i = m0 + (idx >> 4);
        const int c4 = (idx & 15) * 4;
        const float4 vv = *(const float4*)(v + (i * 16 + b) * 64 + c4);
        H[i][c4 + 0] = lrelu(vv.x + us[c4 + 0]);
        H[i][c4 + 1] = lrelu(vv.y + us[c4 + 1]);
        H[i][c4 + 2] = lrelu(vv.z + us[c4 + 2]);
        H[i][c4 + 3] = lrelu(vv.w + us[c4 + 3]);
    }

    const float* mbp[3] = {mb1, mb2, mb3};
    for (int layer = 0; layer < 3; ++layer) {
        const u16* wh = w3h + layer * 4096;
        const u16* wl = w3l + layer * 4096;
        floatx4 acc[2][4];
        #pragma unroll
        for (int i = 0; i < 2; ++i)
            #pragma unroll
            for (int j = 0; j < 4; ++j) acc[i][j] = (floatx4)0.0f;

        #pragma unroll
        for (int kc = 0; kc < 2; ++kc) {
            const int k0 = kc * 32 + quad * 8;
            short8 ah[2], al[2];
            #pragma unroll
            for (int mt = 0; mt < 2; ++mt) {
                const float* hp = &H[m0 + mt * 16 + l15][k0];
                float xv[8];
                *(float4*)(xv)     = *(const float4*)(hp);
                *(float4*)(xv + 4) = *(const float4*)(hp + 4);
                split8(xv, &ah[mt], &al[mt]);
            }
            #pragma unroll
            for (int nt = 0; nt < 4; ++nt) {
                const int boff = (nt * 16 + l15) * 64 + k0;
                const short8 bh = load_frag(wh + boff);
                const short8 bl = load_frag(wl + boff);
                #pragma unroll
                for (int mt = 0; mt < 2; ++mt) {
                    acc[mt][nt] = mfma16(ah[mt], bh, acc[mt][nt]);
                    acc[mt][nt] = mfma16(ah[mt], bl, acc[mt][nt]);
                    acc[mt][nt] = mfma16(al[mt], bh, acc[mt][nt]);
                }
            }
        }

        __syncthreads();   // paranoia: ensure all reads of H done before overwrite
        #pragma unroll
        for (int nt = 0; nt < 4; ++nt) {
            const float bias = mbp[layer][nt * 16 + l15];
            #pragma unroll
            for (int mt = 0; mt < 2; ++mt)
                #pragma unroll
                for (int r = 0; r < 4; ++r)
                    H[m0 + mt * 16 + quad * 4 + r][nt * 16 + l15] =
                        lrelu(acc[mt][nt][r] + bias);
        }
        __syncthreads();
    }

    // S[c] = sum_i H[i][c]
    {
        const int c = t & 63, g = t >> 6;
        float sum = 0.0f;
        #pragma unroll 4
        for (int i = g * 32; i < g * 32 + 32; ++i) sum += H[i][c];
        Sp[g][c] = sum;
    }
    __syncthreads();
    if (t < 64) Ss[t] = Sp[0][t] + Sp[1][t] + Sp[2][t] + Sp[3][t];
    __syncthreads();

    if (t < 64) {
        float a = lb0[t];
        #pragma unroll 4
        for (int k = 0; k < 64; ++k) a += Ss[k] * lw0t[k * 64 + t];
        t1[t] = lrelu(a);
    }
    __syncthreads();

    {
        float a = lb1[t];
        #pragma unroll 4
        for (int k = 0; k < 64; ++k) a += t1[k] * lw1t[k * 256 + t];
        out[jb * 256 + t] = lrelu(a);
    }
}

// ---------------------------------------------------------------------------
extern "C" void kernel_launch(void* const* d_in, const int* in_sizes, int n_in,
                              void* d_out, int out_size, void* d_ws, size_t ws_size,
                              hipStream_t stream)
{
    const float* x   = (const float*)d_in[0];
    const float* cw0 = (const float*)d_in[1];
    const float* cb0 = (const float*)d_in[2];
    const float* cw1 = (const float*)d_in[3];
    const float* cb1 = (const float*)d_in[4];
    const float* cw2 = (const float*)d_in[5];
    const float* cb2 = (const float*)d_in[6];
    const float* cw3 = (const float*)d_in[7];
    const float* cb3 = (const float*)d_in[8];
    const float* mw0 = (const float*)d_in[9];
    const float* mb0 = (const float*)d_in[10];
    const float* mw1 = (const float*)d_in[11];
    const float* mb1 = (const float*)d_in[12];
    const float* mw2 = (const float*)d_in[13];
    const float* mb2 = (const float*)d_in[14];
    const float* mw3 = (const float*)d_in[15];
    const float* mb3 = (const float*)d_in[16];
    const float* lw0 = (const float*)d_in[17];
    const float* lb0 = (const float*)d_in[18];
    const float* lw1 = (const float*)d_in[19];
    const float* lb1 = (const float*)d_in[20];
    float* out = (float*)d_out;

    char* base = (char*)d_ws;
    u16* xh    = (u16*)(base + 0);
    u16* xl    = (u16*)(base + 2097152);
    u16* wch   = (u16*)(base + 4194304);
    u16* wcl   = (u16*)(base + 5242880);
    u16* b2h   = (u16*)(base + 6291456);
    u16* b2l   = (u16*)(base + 6356992);
    u16* w3h   = (u16*)(base + 6422528);
    u16* w3l   = (u16*)(base + 6447104);
    float* lw0t   = (float*)(base + 6471680);
    float* lw1t   = (float*)(base + 6488064);
    float* f_part = (float*)(base + 6553600);
    u16* Fh    = (u16*)(base + 14942208);
    u16* Fl    = (u16*)(base + 15990784);
    float* u   = (float*)(base + 17039360);
    float* v   = (float*)(base + 17563648);
    // total: 18087936 bytes (~17.3 MB)

    hipLaunchKernelGGL(p0_prep, dim3(6400), dim3(256), 0, stream,
                       x, cw0, cw1, cw2, cw3, mw0, mw1, mw2, mw3, lw0, lw1,
                       xh, xl, wch, wcl, b2h, b2l, w3h, w3l, lw0t, lw1t);
    hipLaunchKernelGGL(k1_conv, dim3(256), dim3(256), 0, stream,
                       xh, xl, wch, wcl, f_part);
    hipLaunchKernelGGL(k1b_act, dim3(512), dim3(256), 0, stream,
                       f_part, cb0, cb1, cb2, cb3, Fh, Fl);
    hipLaunchKernelGGL(k2_uv, dim3(16, 2), dim3(256), 0, stream,
                       Fh, Fl, b2h, b2l, mb0, u, v);
    hipLaunchKernelGGL(k3_pair, dim3(2048), dim3(256), 0, stream,
                       u, v, w3h, w3l, mb1, mb2, mb3, lw0t, lb0, lw1t, lb1, out);
}

// Round 3
// 215.999 us; speedup vs baseline: 1.4922x; 1.0033x over previous
//
#include <hip/hip_runtime.h>
#include <hip/hip_bf16.h>

#define SLOPE 0.1f
typedef unsigned short u16;
typedef unsigned int u32;
typedef __attribute__((ext_vector_type(8))) short short8;
typedef __attribute__((ext_vector_type(4))) float floatx4;

__device__ __forceinline__ float lrelu(float x) { return x > 0.0f ? x : SLOPE * x; }

// round-nearest split: x ~= hi + lo (bf16 each), rel err ~2^-17
__device__ __forceinline__ void split_rn(float x, u16* h, u16* l) {
    union { __hip_bfloat16 b; u16 u; } c1, c2;
    c1.b = __float2bfloat16(x);
    float hf = __bfloat162float(c1.b);
    c2.b = __float2bfloat16(x - hf);
    *h = c1.u; *l = c2.u;
}

// truncation split (cheap, ~2^-16 rel): hi = trunc-bf16(x), lo = trunc-bf16(x-hi)
__device__ __forceinline__ void split_t(float x, u16& h, u16& l) {
    u32 ub = __float_as_uint(x);
    float hf = __uint_as_float(ub & 0xFFFF0000u);
    h = (u16)(ub >> 16);
    l = (u16)(__float_as_uint(x - hf) >> 16);
}

__device__ __forceinline__ short8 load_frag(const u16* p) {
    union { uint4 q; short8 s; } cv;
    cv.q = *(const uint4*)p;
    return cv.s;
}

__device__ __forceinline__ floatx4 mfma16(short8 a, short8 b, floatx4 c) {
    return __builtin_amdgcn_mfma_f32_16x16x32_bf16(a, b, c, 0, 0, 0);
}

// ---------------------------------------------------------------------------
// P0: one-shot preprocessing (identical to R2).
// ---------------------------------------------------------------------------
__global__ __launch_bounds__(256) void p0_prep(
    const float* __restrict__ x,
    const float* __restrict__ cw0, const float* __restrict__ cw1,
    const float* __restrict__ cw2, const float* __restrict__ cw3,
    const float* __restrict__ mw0, const float* __restrict__ mw1,
    const float* __restrict__ mw2, const float* __restrict__ mw3,
    const float* __restrict__ lw0, const float* __restrict__ lw1,
    u16* __restrict__ xh, u16* __restrict__ xl,
    u16* __restrict__ wch, u16* __restrict__ wcl,
    u16* __restrict__ b2h, u16* __restrict__ b2l,
    u16* __restrict__ w3h, u16* __restrict__ w3l,
    float* __restrict__ lw0t, float* __restrict__ lw1t)
{
    int idx = blockIdx.x * 256 + threadIdx.x;
    if (idx < 1048576) { split_rn(x[idx], &xh[idx], &xl[idx]); return; }
    idx -= 1048576;
    if (idx < 524288) {
        const int slot = idx >> 15, c = (idx >> 9) & 63, e = idx & 511;
        int branch, base;
        if (slot == 0)      { branch = 0; base = 0; }
        else if (slot < 4)  { branch = 1; base = 1; }
        else if (slot < 9)  { branch = 2; base = 4; }
        else                { branch = 3; base = 9; }
        const int dk = slot - base, ksz = 2 * branch + 1;
        const float* cw = branch == 0 ? cw0 : branch == 1 ? cw1 : branch == 2 ? cw2 : cw3;
        split_rn(cw[(c * ksz + dk) * 512 + e], &wch[idx], &wcl[idx]);
        return;
    }
    idx -= 524288;
    if (idx < 32768) {
        const int n = idx >> 8, k = idx & 255;
        split_rn(mw0[(n & 63) * 512 + (n >> 6) * 256 + k], &b2h[idx], &b2l[idx]);
        return;
    }
    idx -= 32768;
    if (idx < 12288) {
        const int l = idx >> 12, n = (idx >> 6) & 63, k = idx & 63;
        const float* mw = l == 0 ? mw1 : l == 1 ? mw2 : mw3;
        split_rn(mw[n * 64 + k], &w3h[idx], &w3l[idx]);
        return;
    }
    idx -= 12288;
    if (idx < 4096) { const int k = idx >> 6, n = idx & 63; lw0t[idx] = lw0[n * 64 + k]; return; }
    idx -= 4096;
    if (idx < 16384) { const int k = idx >> 8, n = idx & 255; lw1t[idx] = lw1[n * 64 + k]; return; }
}

// ---------------------------------------------------------------------------
// K1: per-(slot) conv-tap GEMM via MFMA, no LDS.  16-row wave tiles for
// 2048 waves (2/SIMD).  grid: 512 blocks (slot*32 + tile), 256 thr = 4 waves.
// ---------------------------------------------------------------------------
__global__ __launch_bounds__(256) void k1_conv(
    const u16* __restrict__ xh, const u16* __restrict__ xl,
    const u16* __restrict__ wch, const u16* __restrict__ wcl,
    float* __restrict__ f_part)
{
    const int t = threadIdx.x, lane = t & 63, w = t >> 6;
    const int slot = blockIdx.x >> 5;
    const int m0 = (blockIdx.x & 31) * 64 + w * 16;
    int branch, base;
    if (slot == 0)      { branch = 0; base = 0; }
    else if (slot < 4)  { branch = 1; base = 1; }
    else if (slot < 9)  { branch = 2; base = 4; }
    else                { branch = 3; base = 9; }
    const int s = (slot - base) - branch;       // tap shift in l-units
    const int l15 = lane & 15, quad = lane >> 4;

    const u16* wbh = wch + slot * 32768;
    const u16* wbl = wcl + slot * 32768;

    floatx4 acc[4];
    #pragma unroll
    for (int j = 0; j < 4; ++j) acc[j] = (floatx4)0.0f;

    const int gbase = m0 + s * 16;              // 16-aligned -> tile uniformly in/out
    const bool ok = (gbase >= 0) && (gbase < 2048);
    const int rowg = gbase + l15;

    const short8 zfrag = {0, 0, 0, 0, 0, 0, 0, 0};
    #pragma unroll 4
    for (int k0 = 0; k0 < 512; k0 += 32) {
        short8 ah, al;
        if (ok) {
            const int off = rowg * 512 + k0 + quad * 8;
            ah = load_frag(xh + off);
            al = load_frag(xl + off);
        } else { ah = zfrag; al = zfrag; }
        #pragma unroll
        for (int nt = 0; nt < 4; ++nt) {
            const int boff = (nt * 16 + l15) * 512 + k0 + quad * 8;
            const short8 bh = load_frag(wbh + boff);
            const short8 bl = load_frag(wbl + boff);
            acc[nt] = mfma16(ah, bh, acc[nt]);
            acc[nt] = mfma16(ah, bl, acc[nt]);
            acc[nt] = mfma16(al, bh, acc[nt]);
        }
    }

    float* fp = f_part + slot * 131072;
    #pragma unroll
    for (int nt = 0; nt < 4; ++nt)
        #pragma unroll
        for (int r = 0; r < 4; ++r)
            fp[(m0 + quad * 4 + r) * 64 + nt * 16 + l15] = acc[nt][r];
}

// ---------------------------------------------------------------------------
// K1b: tap-sum + conv bias + lrelu -> F (2048x256) split to bf16 hi/lo.
// ---------------------------------------------------------------------------
__global__ __launch_bounds__(256) void k1b_act(
    const float* __restrict__ f_part,
    const float* __restrict__ cb0, const float* __restrict__ cb1,
    const float* __restrict__ cb2, const float* __restrict__ cb3,
    u16* __restrict__ Fh, u16* __restrict__ Fl)
{
    const int idx = blockIdx.x * 256 + threadIdx.x;   // 131072
    const int r = idx >> 6, m4 = (idx & 63) * 4;
    const int branch = m4 >> 6, c = m4 & 63;
    int base, ksz; const float* cb;
    if (branch == 0)      { base = 0; ksz = 1; cb = cb0; }
    else if (branch == 1) { base = 1; ksz = 3; cb = cb1; }
    else if (branch == 2) { base = 4; ksz = 5; cb = cb2; }
    else                  { base = 9; ksz = 7; cb = cb3; }
    float4 sum = *(const float4*)(cb + c);
    const float* fp = f_part + base * 131072 + r * 64 + c;
    for (int d = 0; d < ksz; ++d) {
        const float4 p = *(const float4*)(fp + d * 131072);
        sum.x += p.x; sum.y += p.y; sum.z += p.z; sum.w += p.w;
    }
    float v4[4] = {lrelu(sum.x), lrelu(sum.y), lrelu(sum.z), lrelu(sum.w)};
    u16 h4[4], l4[4];
    #pragma unroll
    for (int i = 0; i < 4; ++i) split_rn(v4[i], &h4[i], &l4[i]);
    *(ushort4*)(Fh + r * 256 + m4) = make_ushort4(h4[0], h4[1], h4[2], h4[3]);
    *(ushort4*)(Fl + r * 256 + m4) = make_ushort4(l4[0], l4[1], l4[2], l4[3]);
}

// ---------------------------------------------------------------------------
// K2: [u|v] = F @ B2^T via MFMA, no LDS.  Single-wave blocks of 16 rows x
// 64 cols for 256 blocks spread over CUs.  u gets + mb0.
// ---------------------------------------------------------------------------
__global__ __launch_bounds__(64) void k2_uv(
    const u16* __restrict__ Fh, const u16* __restrict__ Fl,
    const u16* __restrict__ b2h, const u16* __restrict__ b2l,
    const float* __restrict__ mb0,
    float* __restrict__ u, float* __restrict__ v)
{
    const int lane = threadIdx.x & 63;
    const int m0 = blockIdx.x * 16;
    const int nhalf = blockIdx.y;
    const int l15 = lane & 15, quad = lane >> 4;

    floatx4 acc[4];
    #pragma unroll
    for (int j = 0; j < 4; ++j) acc[j] = (floatx4)0.0f;

    #pragma unroll 4
    for (int k0 = 0; k0 < 256; k0 += 32) {
        const int off = (m0 + l15) * 256 + k0 + quad * 8;
        const short8 ah = load_frag(Fh + off);
        const short8 al = load_frag(Fl + off);
        #pragma unroll
        for (int nt = 0; nt < 4; ++nt) {
            const int boff = (nhalf * 64 + nt * 16 + l15) * 256 + k0 + quad * 8;
            const short8 bh = load_frag(b2h + boff);
            const short8 bl = load_frag(b2l + boff);
            acc[nt] = mfma16(ah, bh, acc[nt]);
            acc[nt] = mfma16(ah, bl, acc[nt]);
            acc[nt] = mfma16(al, bh, acc[nt]);
        }
    }

    #pragma unroll
    for (int nt = 0; nt < 4; ++nt) {
        const int c = nt * 16 + l15;
        #pragma unroll
        for (int r = 0; r < 4; ++r) {
            const int row = m0 + quad * 4 + r;
            const float val = acc[nt][r];
            if (nhalf == 0) u[row * 64 + c] = val + mb0[c];
            else            v[row * 64 + c] = val;
        }
    }
}

// ---------------------------------------------------------------------------
// K3 (transposed form): per (j,b), H stored [i][ch] bf16 hi/lo in LDS,
// wave-private 32-i strips -> ZERO barriers across the 3 MFMA layers.
// Layer: H'^T = lrelu(W*H^T + b): A = W (global row-major hi/lo, L1-hot),
// B = H rows (contiguous b128 LDS reads), D (row=ch, col=i) written back as
// ushort4 hi/lo.  Then per-wave i-sum, cross-wave reduce, fp32 head.
// grid: 2048 blocks, 256 thr = 4 waves.
// ---------------------------------------------------------------------------
__global__ __launch_bounds__(256, 4) void k3_pair(
    const float* __restrict__ u, const float* __restrict__ v,
    const u16* __restrict__ w3h, const u16* __restrict__ w3l,
    const float* __restrict__ mb1, const float* __restrict__ mb2,
    const float* __restrict__ mb3,
    const float* __restrict__ lw0t, const float* __restrict__ lb0,
    const float* __restrict__ lw1t, const float* __restrict__ lb1,
    float* __restrict__ out)
{
    // stride 72 u16 = 144 B: rows 16B-aligned; b128 reads land uniform 8/bank
    __shared__ __align__(16) u16 Hh[128][72];
    __shared__ __align__(16) u16 Hl[128][72];
    __shared__ float us[64];
    __shared__ float Sp[4][64];
    __shared__ float Ss[64];
    __shared__ float t1[64];

    const int t = threadIdx.x, lane = t & 63, w = t >> 6;
    const int jb = blockIdx.x, b = jb & 15;
    const int l15 = lane & 15, quad = lane >> 4;
    const int m0 = w * 32;                      // this wave's i-strip

    if (t < 64) us[t] = u[jb * 64 + t];
    __syncthreads();

    // H1[i][ch] = lrelu(u[jb][ch] + v[i*16+b][ch]), wave-private rows
    #pragma unroll
    for (int n = 0; n < 8; ++n) {
        const int i  = m0 + 4 * n + quad;
        const int c4 = l15 * 4;
        const float4 vv = *(const float4*)(v + (i * 16 + b) * 64 + c4);
        const float4 uu = *(const float4*)(&us[c4]);
        float a0 = lrelu(vv.x + uu.x), a1 = lrelu(vv.y + uu.y);
        float a2 = lrelu(vv.z + uu.z), a3 = lrelu(vv.w + uu.w);
        ushort4 ph, pl;
        split_t(a0, ph.x, pl.x); split_t(a1, ph.y, pl.y);
        split_t(a2, ph.z, pl.z); split_t(a3, ph.w, pl.w);
        *(ushort4*)&Hh[i][c4] = ph;
        *(ushort4*)&Hl[i][c4] = pl;
    }

    const float* mbp[3] = {mb1, mb2, mb3};
    for (int layer = 0; layer < 3; ++layer) {
        const u16* wh = w3h + layer * 4096;
        const u16* wl = w3l + layer * 4096;
        floatx4 acc[4][2];                      // [mt = ch-tile][nt = i-tile]
        #pragma unroll
        for (int i = 0; i < 4; ++i)
            #pragma unroll
            for (int j = 0; j < 2; ++j) acc[i][j] = (floatx4)0.0f;

        #pragma unroll
        for (int kc = 0; kc < 2; ++kc) {
            const int k0 = kc * 32 + quad * 8;
            short8 bhf[2], blf[2];
            #pragma unroll
            for (int nt = 0; nt < 2; ++nt) {
                bhf[nt] = load_frag(&Hh[m0 + nt * 16 + l15][k0]);
                blf[nt] = load_frag(&Hl[m0 + nt * 16 + l15][k0]);
            }
            #pragma unroll
            for (int mt = 0; mt < 4; ++mt) {
                const short8 ah = load_frag(wh + (mt * 16 + l15) * 64 + k0);
                const short8 al = load_frag(wl + (mt * 16 + l15) * 64 + k0);
                #pragma unroll
                for (int nt = 0; nt < 2; ++nt) {
                    acc[mt][nt] = mfma16(ah, bhf[nt], acc[mt][nt]);
                    acc[mt][nt] = mfma16(ah, blf[nt], acc[mt][nt]);
                    acc[mt][nt] = mfma16(al, bhf[nt], acc[mt][nt]);
                }
            }
        }

        // epilogue: bias + lrelu + split, write back wave-private (no barrier)
        #pragma unroll
        for (int mt = 0; mt < 4; ++mt) {
            float bias[4];
            #pragma unroll
            for (int r = 0; r < 4; ++r) bias[r] = mbp[layer][mt * 16 + quad * 4 + r];
            #pragma unroll
            for (int nt = 0; nt < 2; ++nt) {
                const int i = m0 + nt * 16 + l15;
                float v0 = lrelu(acc[mt][nt][0] + bias[0]);
                float v1 = lrelu(acc[mt][nt][1] + bias[1]);
                float v2 = lrelu(acc[mt][nt][2] + bias[2]);
                float v3 = lrelu(acc[mt][nt][3] + bias[3]);
                ushort4 ph, pl;
                split_t(v0, ph.x, pl.x); split_t(v1, ph.y, pl.y);
                split_t(v2, ph.z, pl.z); split_t(v3, ph.w, pl.w);
                *(ushort4*)&Hh[i][mt * 16 + quad * 4] = ph;
                *(ushort4*)&Hl[i][mt * 16 + quad * 4] = pl;
            }
        }
    }

    // per-wave i-sum: lane = ch, sum own 32 rows (hi + lo)
    {
        float s = 0.0f;
        #pragma unroll 8
        for (int ii = 0; ii < 32; ++ii) {
            const u32 hv = Hh[m0 + ii][lane];
            const u32 lv = Hl[m0 + ii][lane];
            s += __uint_as_float(hv << 16) + __uint_as_float(lv << 16);
        }
        Sp[w][lane] = s;
    }
    __syncthreads();

    if (t < 64) Ss[t] = Sp[0][t] + Sp[1][t] + Sp[2][t] + Sp[3][t];
    __syncthreads();

    // head layer 1: 64 -> 64
    if (t < 64) {
        float a = lb0[t];
        #pragma unroll 8
        for (int k = 0; k < 64; ++k) a += Ss[k] * lw0t[k * 64 + t];
        t1[t] = lrelu(a);
    }
    __syncthreads();

    // head layer 2: 64 -> 256 (one output per thread)
    {
        float a = lb1[t];
        #pragma unroll 8
        for (int k = 0; k < 64; ++k) a += t1[k] * lw1t[k * 256 + t];
        out[jb * 256 + t] = lrelu(a);
    }
}

// ---------------------------------------------------------------------------
extern "C" void kernel_launch(void* const* d_in, const int* in_sizes, int n_in,
                              void* d_out, int out_size, void* d_ws, size_t ws_size,
                              hipStream_t stream)
{
    const float* x   = (const float*)d_in[0];
    const float* cw0 = (const float*)d_in[1];
    const float* cb0 = (const float*)d_in[2];
    const float* cw1 = (const float*)d_in[3];
    const float* cb1 = (const float*)d_in[4];
    const float* cw2 = (const float*)d_in[5];
    const float* cb2 = (const float*)d_in[6];
    const float* cw3 = (const float*)d_in[7];
    const float* cb3 = (const float*)d_in[8];
    const float* mw0 = (const float*)d_in[9];
    const float* mb0 = (const float*)d_in[10];
    const float* mw1 = (const float*)d_in[11];
    const float* mb1 = (const float*)d_in[12];
    const float* mw2 = (const float*)d_in[13];
    const float* mb2 = (const float*)d_in[14];
    const float* mw3 = (const float*)d_in[15];
    const float* mb3 = (const float*)d_in[16];
    const float* lw0 = (const float*)d_in[17];
    const float* lb0 = (const float*)d_in[18];
    const float* lw1 = (const float*)d_in[19];
    const float* lb1 = (const float*)d_in[20];
    float* out = (float*)d_out;

    char* base = (char*)d_ws;
    u16* xh    = (u16*)(base + 0);
    u16* xl    = (u16*)(base + 2097152);
    u16* wch   = (u16*)(base + 4194304);
    u16* wcl   = (u16*)(base + 5242880);
    u16* b2h   = (u16*)(base + 6291456);
    u16* b2l   = (u16*)(base + 6356992);
    u16* w3h   = (u16*)(base + 6422528);
    u16* w3l   = (u16*)(base + 6447104);
    float* lw0t   = (float*)(base + 6471680);
    float* lw1t   = (float*)(base + 6488064);
    float* f_part = (float*)(base + 6553600);
    u16* Fh    = (u16*)(base + 14942208);
    u16* Fl    = (u16*)(base + 15990784);
    float* u   = (float*)(base + 17039360);
    float* v   = (float*)(base + 17563648);
    // total: 18087936 bytes (~17.3 MB)

    hipLaunchKernelGGL(p0_prep, dim3(6400), dim3(256), 0, stream,
                       x, cw0, cw1, cw2, cw3, mw0, mw1, mw2, mw3, lw0, lw1,
                       xh, xl, wch, wcl, b2h, b2l, w3h, w3l, lw0t, lw1t);
    hipLaunchKernelGGL(k1_conv, dim3(512), dim3(256), 0, stream,
                       xh, xl, wch, wcl, f_part);
    hipLaunchKernelGGL(k1b_act, dim3(512), dim3(256), 0, stream,
                       f_part, cb0, cb1, cb2, cb3, Fh, Fl);
    hipLaunchKernelGGL(k2_uv, dim3(128, 2), dim3(64), 0, stream,
                       Fh, Fl, b2h, b2l, mb0, u, v);
    hipLaunchKernelGGL(k3_pair, dim3(2048), dim3(256), 0, stream,
                       u, v, w3h, w3l, mb1, mb2, mb3, lw0t, lb0, lw1t, lb1, out);
}